// Round 1
// baseline (496.547 us; speedup 1.0000x reference)
//
#include <hip/hip_runtime.h>
#include <hip/hip_bf16.h>
#include <stdint.h>

// Problem constants
#define B_    16
#define CIN   256
#define COUT  256
#define E_    8
#define HW    1024   // 32x32

typedef __attribute__((ext_vector_type(8))) short  short8;
typedef __attribute__((ext_vector_type(4))) float  floatx4;

// Workspace layout (bytes):
//   [0,64)        : decisions int[16]
//   [64,16448)    : pooled float[16*256]
//   [17408, +8MB) : xt bf16 [16][32][32][256]  (NHWC)
//   [WT_OFF,+9MB) : wt bf16 [8][9][256][256]   ([e][r*3+s][co][ci])
#define XT_OFF 17408
#define WT_OFF (XT_OFF + B_*HW*CIN*2)

// ---------------- Kernel 1: global average pool (fp32, exact-ish) ----------------
__global__ void pool_kernel(const float* __restrict__ x, float* __restrict__ pooled) {
    int b = blockIdx.x, c = blockIdx.y;
    const float4* p = (const float4*)(x + ((size_t)b*CIN + c)*HW);
    int t = threadIdx.x;
    float4 v = p[t];                      // 256 threads * 4 = 1024 elems
    float s = v.x + v.y + v.z + v.w;
    #pragma unroll
    for (int o = 32; o > 0; o >>= 1) s += __shfl_down(s, o, 64);
    __shared__ float wsum[4];
    if ((t & 63) == 0) wsum[t >> 6] = s;
    __syncthreads();
    if (t == 0) pooled[b*CIN + c] = (wsum[0]+wsum[1]+wsum[2]+wsum[3]) * (1.0f/1024.0f);
}

// ---------------- Kernel 2: logits + argmax -> decisions ----------------
__global__ void decide_kernel(const float* __restrict__ pooled, const float* __restrict__ wc,
                              const float* __restrict__ bc, int* __restrict__ dec) {
    int t = threadIdx.x;          // 128 threads: b = t/8, e = t%8
    int b = t >> 3, e = t & 7;
    float acc = bc[e];
    const float* pp = pooled + b*CIN;
    const float* ww = wc + e*CIN;
    for (int i = 0; i < CIN; ++i) acc += pp[i] * ww[i];
    __shared__ float lg[16][8];
    lg[b][e] = acc;
    __syncthreads();
    if (e == 0) {
        float best = lg[b][0]; int bi = 0;
        #pragma unroll
        for (int j = 1; j < 8; ++j) { if (lg[b][j] > best) { best = lg[b][j]; bi = j; } }
        dec[b] = bi;
    }
}

// ---------------- Kernel 3: x NCHW fp32 -> NHWC bf16 ----------------
__global__ void xpose_kernel(const float* __restrict__ x, unsigned short* __restrict__ xt) {
    // grid (16, 32, 8): b, hw-tile (32 hw), ci-tile (32 ci); 256 threads
    int b = blockIdx.x;
    int hw0 = blockIdx.y * 32;
    int ci0 = blockIdx.z * 32;
    __shared__ float tile[32][33];
    int t = threadIdx.x;
    int j = t & 31;      // hw within tile (read phase)
    int i = t >> 5;      // ci sub-row 0..7
    #pragma unroll
    for (int p = 0; p < 4; ++p)
        tile[i + p*8][j] = x[((size_t)b*CIN + ci0 + i + p*8)*HW + hw0 + j];
    __syncthreads();
    int cw = t & 31;     // ci within tile (write phase)
    int rw = t >> 5;     // hw sub-row 0..7
    #pragma unroll
    for (int p = 0; p < 4; ++p) {
        int hw = hw0 + rw + p*8;
        __hip_bfloat16 h = __float2bfloat16(tile[cw][rw + p*8]);
        xt[((size_t)b*HW + hw)*CIN + ci0 + cw] = *(unsigned short*)&h;
    }
}

// ---------------- Kernel 4: we [e][co][ci][3][3] fp32 -> wt [e][rs][co][ci] bf16 ----------------
__global__ void wpose_kernel(const float* __restrict__ we, unsigned short* __restrict__ wt) {
    int ec = blockIdx.x;            // 2048 blocks: e*256+co
    int e = ec >> 8, co = ec & 255;
    int ci = threadIdx.x;           // 256 threads
    const float* src = we + (((size_t)e*COUT + co)*CIN + ci)*9;
    #pragma unroll
    for (int rs = 0; rs < 9; ++rs) {
        __hip_bfloat16 h = __float2bfloat16(src[rs]);
        wt[(((size_t)e*9 + rs)*COUT + co)*CIN + ci] = *(unsigned short*)&h;
    }
}

// ---------------- Kernel 5: shift-decomposed implicit-GEMM conv + gather-write ----------------
// grid: x = mt*8+nt (16 tiles of the 256x1024 output), y = b (16), z = e (8); 256 threads
__global__ __launch_bounds__(256) void conv_kernel(
    const unsigned short* __restrict__ xt, const unsigned short* __restrict__ wt,
    const float* __restrict__ be, const int* __restrict__ dec,
    float* __restrict__ out) {

    int tile = blockIdx.x;
    int b = blockIdx.y;
    int e = blockIdx.z;
    int mt = tile >> 3, nt = tile & 7;

    // which output slots i use this expert?
    int dcs[16];
    #pragma unroll
    for (int i = 0; i < 16; ++i) dcs[i] = dec[i];
    bool active = false;
    #pragma unroll
    for (int i = 0; i < 16; ++i) active |= (dcs[i] == e);
    if (!active) return;   // uniform across block

    __shared__ __align__(16) unsigned short sA[128*32];      // [co][ci]   8 KB
    __shared__ __align__(16) unsigned short sB[6*34*32];     // [row][col][ci] 13 KB, col/row zero-padded halo

    int t = threadIdx.x;
    int wave = t >> 6, lane = t & 63;
    int wm = wave >> 1, wn = wave & 1;     // 2x2 wave grid, 64x64 per wave
    int kg = lane >> 4, ln = lane & 15;

    int h0  = nt * 4;       // output rows h0..h0+3
    int co0 = mt * 128;

    floatx4 acc[4][4];
    #pragma unroll
    for (int i = 0; i < 4; ++i)
        #pragma unroll
        for (int j = 0; j < 4; ++j) acc[i][j] = (floatx4)0.0f;

    const unsigned short* xb = xt + (size_t)b*HW*CIN;

    for (int ck = 0; ck < 8; ++ck) {
        int ci0 = ck * 32;
        // ---- stage B: x halo rows h0-1..h0+4, cols -1..32, 32 ci -> [6][34][32] ----
        for (int c = t; c < 816; c += 256) {          // 816 chunks of 16 B
            int ci16 = c & 3;
            int col  = (c >> 2) % 34;
            int row  = c / 136;
            int gh = h0 - 1 + row;
            int gw = col - 1;
            uint4 v = make_uint4(0u, 0u, 0u, 0u);
            if (gh >= 0 && gh < 32 && gw >= 0 && gw < 32)
                v = *(const uint4*)(xb + ((size_t)gh*32 + gw)*CIN + ci0 + ci16*8);
            *(uint4*)(&sB[(row*34 + col)*32 + ci16*8]) = v;
        }
        for (int sh = 0; sh < 9; ++sh) {
            // ---- stage A: wt[e][sh][co0..co0+128][ci0..ci0+32] -> [128][32] ----
            const unsigned short* wsrc = wt + (((size_t)e*9 + sh)*COUT + co0)*CIN + ci0;
            {
                int rowA = t >> 2;
                int cip  = (t & 3) * 8;
                *(uint4*)(&sA[rowA*32 + cip])      = *(const uint4*)(wsrc + (size_t)rowA*CIN + cip);
                *(uint4*)(&sA[(rowA+64)*32 + cip]) = *(const uint4*)(wsrc + (size_t)(rowA+64)*CIN + cip);
            }
            __syncthreads();

            short8 a[4], bb[4];
            #pragma unroll
            for (int im = 0; im < 4; ++im)
                a[im] = *(const short8*)(&sA[(wm*64 + im*16 + ln)*32 + kg*8]);
            int r = sh / 3, s = sh % 3;
            #pragma unroll
            for (int in = 0; in < 4; ++in) {
                int n  = wn*64 + in*16 + ln;
                int hl = n >> 5, wl = n & 31;
                bb[in] = *(const short8*)(&sB[((hl + r)*34 + (wl + s))*32 + kg*8]);
            }
            __syncthreads();   // frag reads done; next staging may overlap MFMA

            #pragma unroll
            for (int im = 0; im < 4; ++im)
                #pragma unroll
                for (int in = 0; in < 4; ++in)
                    acc[im][in] = __builtin_amdgcn_mfma_f32_16x16x32_bf16(a[im], bb[in], acc[im][in], 0, 0, 0);
        }
    }

    // ---- epilogue: bias + relu in place ----
    #pragma unroll
    for (int im = 0; im < 4; ++im) {
        int co = co0 + wm*64 + im*16 + kg*4;
        #pragma unroll
        for (int rg = 0; rg < 4; ++rg) {
            float bv = be[e*COUT + co + rg];
            #pragma unroll
            for (int in = 0; in < 4; ++in) {
                float v = acc[im][in][rg] + bv;
                acc[im][in][rg] = v > 0.0f ? v : 0.0f;
            }
        }
    }
    // ---- write to every output slot i with dec[i]==e ----
    for (int i = 0; i < 16; ++i) {
        if (dcs[i] != e) continue;
        float* ob = out + (size_t)(i*16 + b)*COUT*HW;
        #pragma unroll
        for (int im = 0; im < 4; ++im) {
            int co = co0 + wm*64 + im*16 + kg*4;
            #pragma unroll
            for (int in = 0; in < 4; ++in) {
                int hw = nt*128 + wn*64 + in*16 + ln;
                #pragma unroll
                for (int rg = 0; rg < 4; ++rg)
                    ob[(size_t)(co + rg)*HW + hw] = acc[im][in][rg];
            }
        }
    }
}

extern "C" void kernel_launch(void* const* d_in, const int* in_sizes, int n_in,
                              void* d_out, int out_size, void* d_ws, size_t ws_size,
                              hipStream_t stream) {
    const float* x  = (const float*)d_in[0];
    const float* wc = (const float*)d_in[1];
    const float* bc = (const float*)d_in[2];
    const float* we = (const float*)d_in[3];
    const float* be = (const float*)d_in[4];
    float* out = (float*)d_out;

    char* ws = (char*)d_ws;
    int*   dec    = (int*)ws;
    float* pooled = (float*)(ws + 64);
    unsigned short* xt = (unsigned short*)(ws + XT_OFF);
    unsigned short* wt = (unsigned short*)(ws + WT_OFF);

    pool_kernel  <<<dim3(16, 256), 256, 0, stream>>>(x, pooled);
    decide_kernel<<<1, 128, 0, stream>>>(pooled, wc, bc, dec);
    xpose_kernel <<<dim3(16, 32, 8), 256, 0, stream>>>(x, xt);
    wpose_kernel <<<2048, 256, 0, stream>>>(we, wt);
    conv_kernel  <<<dim3(16, 16, 8), 256, 0, stream>>>(xt, wt, be, dec, out);
}

// Round 2
// 469.221 us; speedup vs baseline: 1.0582x; 1.0582x over previous
//
#include <hip/hip_runtime.h>
#include <hip/hip_bf16.h>
#include <stdint.h>

// Problem constants
#define B_    16
#define CIN   256
#define COUT  256
#define E_    8
#define HW    1024   // 32x32
#define PH    34     // padded H (zero halo)
#define PW    34

typedef __attribute__((ext_vector_type(8))) short  short8;
typedef __attribute__((ext_vector_type(4))) float  floatx4;

// Workspace layout (bytes):
//   [0,64)      : decisions int[16]
//   [64,16448)  : pooled float[16*256]
//   [XT_OFF,..) : xt bf16 [16][34][34][256]  (padded NHWC, zero halo)
//   [WT_OFF,..) : wt bf16 [8][9][256][256]   ([e][r*3+s][co][ci])
#define XT_OFF 17408
#define XT_BYTES (B_*PH*PW*CIN*2)               // 9,469,952
#define WT_OFF (XT_OFF + XT_BYTES)

// async global->LDS, 16B per lane. LDS dest is wave-uniform base + lane*16:
// caller must ensure lane-contiguous lds addresses within each wave.
__device__ __forceinline__ void gld_lds16(const void* g, void* l) {
    __builtin_amdgcn_global_load_lds(
        (const __attribute__((address_space(1))) unsigned int*)g,
        (__attribute__((address_space(3))) unsigned int*)l,
        16, 0, 0);
}

// ---------------- Kernel 1: global average pool ----------------
__global__ void pool_kernel(const float* __restrict__ x, float* __restrict__ pooled) {
    int b = blockIdx.x, c = blockIdx.y;
    const float4* p = (const float4*)(x + ((size_t)b*CIN + c)*HW);
    int t = threadIdx.x;
    float4 v = p[t];                      // 256 threads * 4 = 1024 elems
    float s = v.x + v.y + v.z + v.w;
    #pragma unroll
    for (int o = 32; o > 0; o >>= 1) s += __shfl_down(s, o, 64);
    __shared__ float wsum[4];
    if ((t & 63) == 0) wsum[t >> 6] = s;
    __syncthreads();
    if (t == 0) pooled[b*CIN + c] = (wsum[0]+wsum[1]+wsum[2]+wsum[3]) * (1.0f/1024.0f);
}

// ---------------- Kernel 2: logits + argmax -> decisions ----------------
__global__ void decide_kernel(const float* __restrict__ pooled, const float* __restrict__ wc,
                              const float* __restrict__ bc, int* __restrict__ dec) {
    int t = threadIdx.x;          // 128 threads: b = t/8, e = t%8
    int b = t >> 3, e = t & 7;
    float acc = bc[e];
    const float4* pp = (const float4*)(pooled + b*CIN);
    const float4* ww = (const float4*)(wc + e*CIN);
    #pragma unroll 4
    for (int i = 0; i < CIN/4; ++i) {
        float4 p = pp[i], w = ww[i];
        acc += p.x*w.x + p.y*w.y + p.z*w.z + p.w*w.w;
    }
    __shared__ float lg[16][8];
    lg[b][e] = acc;
    __syncthreads();
    if (e == 0) {
        float best = lg[b][0]; int bi = 0;
        #pragma unroll
        for (int j = 1; j < 8; ++j) { if (lg[b][j] > best) { best = lg[b][j]; bi = j; } }
        dec[b] = bi;
    }
}

// ---------------- Kernel 3: x NCHW fp32 -> padded NHWC bf16 ----------------
__global__ void xpose_kernel(const float* __restrict__ x, unsigned short* __restrict__ xt) {
    // grid (16, 32, 8): b, hw-tile (32 hw), ci-tile (32 ci); 256 threads
    int b = blockIdx.x;
    int hw0 = blockIdx.y * 32;
    int ci0 = blockIdx.z * 32;
    __shared__ float tile[32][33];
    int t = threadIdx.x;
    int j = t & 31;      // hw within tile (read phase)
    int i = t >> 5;      // ci sub-row 0..7
    #pragma unroll
    for (int p = 0; p < 4; ++p)
        tile[i + p*8][j] = x[((size_t)b*CIN + ci0 + i + p*8)*HW + hw0 + j];
    __syncthreads();
    int cw = t & 31;     // ci within tile (write phase)
    int rw = t >> 5;     // hw sub-row 0..7
    #pragma unroll
    for (int p = 0; p < 4; ++p) {
        int hw = hw0 + rw + p*8;
        int h = hw >> 5, w = hw & 31;
        __hip_bfloat16 hv = __float2bfloat16(tile[cw][rw + p*8]);
        xt[(((size_t)b*PH + h + 1)*PW + (w + 1))*CIN + ci0 + cw] = *(unsigned short*)&hv;
    }
}

// ---------------- Kernel 4: we [e][co][ci][3][3] fp32 -> wt [e][rs][co][ci] bf16 ----------------
__global__ void wpose_kernel(const float* __restrict__ we, unsigned short* __restrict__ wt) {
    // block = (e, co): 2048 blocks, 256 threads; coalesced read through LDS
    int e = blockIdx.x >> 8, co = blockIdx.x & 255;
    __shared__ float buf[CIN*9];
    const float* src = we + ((size_t)e*COUT + co)*CIN*9;
    int t = threadIdx.x;
    #pragma unroll
    for (int k = 0; k < 9; ++k) buf[t + k*256] = src[t + k*256];
    __syncthreads();
    // thread t = ci; stride-9 LDS read is conflict-free (odd stride)
    #pragma unroll
    for (int rs = 0; rs < 9; ++rs) {
        __hip_bfloat16 h = __float2bfloat16(buf[t*9 + rs]);
        wt[(((size_t)e*9 + rs)*COUT + co)*CIN + t] = *(unsigned short*)&h;
    }
}

// ---------------- Kernel 5: shift-decomposed implicit-GEMM conv + gather-write ----------------
// grid: x = mt*8+nt (16 tiles of the 256x1024 output), y = b (16), z = e (8); 256 threads
__global__ __launch_bounds__(256) void conv_kernel(
    const unsigned short* __restrict__ xt, const unsigned short* __restrict__ wt,
    const float* __restrict__ be, const int* __restrict__ dec,
    float* __restrict__ out) {

    int tile = blockIdx.x;
    int b = blockIdx.y;
    int e = blockIdx.z;
    int mt = tile >> 3, nt = tile & 7;

    int dcs[16];
    #pragma unroll
    for (int i = 0; i < 16; ++i) dcs[i] = dec[i];
    bool active = false;
    #pragma unroll
    for (int i = 0; i < 16; ++i) active |= (dcs[i] == e);
    if (!active) return;   // uniform across block

    // chunk-linear LDS: chunk c occupies bytes [c*16, c*16+16)
    // sA: c = row*4 + g        -> A[row][ci = g*8 .. g*8+8)        (8 KB)
    // sB: c = (row*34+col)*4+g -> x[ph0+row][col][ci0+g*8..+8)     (16 KB, 816 live + 208 pad)
    __shared__ __align__(16) unsigned short sA[512*8];
    __shared__ __align__(16) unsigned short sB[1024*8];

    int t = threadIdx.x;
    int wave = t >> 6, lane = t & 63;
    int wm = wave >> 1, wn = wave & 1;     // 2x2 wave grid, 64x64 per wave
    int kg = lane >> 4, ln = lane & 15;

    int ph0 = nt * 4;       // padded halo start row (output rows h0..h0+3 -> padded h0..h0+5)
    int co0 = mt * 128;

    floatx4 acc[4][4];
    #pragma unroll
    for (int i = 0; i < 4; ++i)
        #pragma unroll
        for (int j = 0; j < 4; ++j) acc[i][j] = (floatx4)0.0f;

    const unsigned short* xb = xt + (size_t)b*PH*PW*CIN;

    for (int ck = 0; ck < 8; ++ck) {
        int ci0 = ck * 32;
        // ---- stage B via global_load_lds: 1024 chunks (816 real, 208 clamped to dead LDS) ----
        #pragma unroll
        for (int k = 0; k < 4; ++k) {
            int c = t + k*256;
            int cc = c < 816 ? c : 815;          // keep all lanes active; tail lands in dead LDS
            int row = cc / 136;                  // 136 = 34 cols * 4 ci-chunks
            int rem = cc - row*136;
            int col = rem >> 2;
            int g   = rem & 3;
            gld_lds16(xb + ((size_t)(ph0 + row)*PW + col)*CIN + ci0 + g*8, &sB[c*8]);
        }
        for (int sh = 0; sh < 9; ++sh) {
            // ---- stage A via global_load_lds: 512 chunks ----
            const unsigned short* wsrc = wt + (((size_t)e*9 + sh)*COUT + co0)*CIN + ci0;
            #pragma unroll
            for (int k = 0; k < 2; ++k) {
                int c = t + k*256;
                int rowA = c >> 2, g = c & 3;
                gld_lds16(wsrc + (size_t)rowA*CIN + g*8, &sA[c*8]);
            }
            __syncthreads();   // drains vmcnt(0): staging complete

            short8 a[4], bb[4];
            #pragma unroll
            for (int im = 0; im < 4; ++im)
                a[im] = *(const short8*)(&sA[((wm*64 + im*16 + ln)*4 + kg)*8]);
            int r = sh / 3, s = sh - r*3;
            #pragma unroll
            for (int in = 0; in < 4; ++in) {
                int n  = wn*64 + in*16 + ln;
                int hl = n >> 5, wl = n & 31;
                bb[in] = *(const short8*)(&sB[(((hl + r)*34 + (wl + s))*4 + kg)*8]);
            }
            __syncthreads();   // frag reads done; next staging may overwrite

            #pragma unroll
            for (int im = 0; im < 4; ++im)
                #pragma unroll
                for (int in = 0; in < 4; ++in)
                    acc[im][in] = __builtin_amdgcn_mfma_f32_16x16x32_bf16(a[im], bb[in], acc[im][in], 0, 0, 0);
        }
    }

    // ---- epilogue: bias + relu in place ----
    #pragma unroll
    for (int im = 0; im < 4; ++im) {
        int co = co0 + wm*64 + im*16 + kg*4;
        #pragma unroll
        for (int rg = 0; rg < 4; ++rg) {
            float bv = be[e*COUT + co + rg];
            #pragma unroll
            for (int in = 0; in < 4; ++in) {
                float v = acc[im][in][rg] + bv;
                acc[im][in][rg] = v > 0.0f ? v : 0.0f;
            }
        }
    }
    // ---- write to every output slot i with dec[i]==e ----
    for (int i = 0; i < 16; ++i) {
        if (dcs[i] != e) continue;
        float* ob = out + (size_t)(i*16 + b)*COUT*HW;
        #pragma unroll
        for (int im = 0; im < 4; ++im) {
            int co = co0 + wm*64 + im*16 + kg*4;
            #pragma unroll
            for (int in = 0; in < 4; ++in) {
                int hw = nt*128 + wn*64 + in*16 + ln;
                #pragma unroll
                for (int rg = 0; rg < 4; ++rg)
                    ob[(size_t)(co + rg)*HW + hw] = acc[im][in][rg];
            }
        }
    }
}

extern "C" void kernel_launch(void* const* d_in, const int* in_sizes, int n_in,
                              void* d_out, int out_size, void* d_ws, size_t ws_size,
                              hipStream_t stream) {
    const float* x  = (const float*)d_in[0];
    const float* wc = (const float*)d_in[1];
    const float* bc = (const float*)d_in[2];
    const float* we = (const float*)d_in[3];
    const float* be = (const float*)d_in[4];
    float* out = (float*)d_out;

    char* ws = (char*)d_ws;
    int*   dec    = (int*)ws;
    float* pooled = (float*)(ws + 64);
    unsigned short* xt = (unsigned short*)(ws + XT_OFF);
    unsigned short* wt = (unsigned short*)(ws + WT_OFF);

    // zero the padded halo of xt (ws is re-poisoned 0xAA before every launch)
    hipMemsetAsync(xt, 0, XT_BYTES, stream);

    pool_kernel  <<<dim3(16, 256), 256, 0, stream>>>(x, pooled);
    decide_kernel<<<1, 128, 0, stream>>>(pooled, wc, bc, dec);
    xpose_kernel <<<dim3(16, 32, 8), 256, 0, stream>>>(x, xt);
    wpose_kernel <<<2048, 256, 0, stream>>>(we, wt);
    conv_kernel  <<<dim3(16, 16, 8), 256, 0, stream>>>(xt, wt, be, dec, out);
}

// Round 3
// 464.723 us; speedup vs baseline: 1.0685x; 1.0097x over previous
//
#include <hip/hip_runtime.h>
#include <hip/hip_bf16.h>
#include <stdint.h>

// Problem constants
#define B_    16
#define CIN   256
#define COUT  256
#define E_    8
#define HW    1024   // 32x32
#define PH    34     // padded H (zero halo)
#define PW    34

typedef __attribute__((ext_vector_type(8))) short  short8;
typedef __attribute__((ext_vector_type(4))) float  floatx4;

// Workspace layout (bytes):
//   [0,64)      : decisions int[16]
//   [64,16448)  : pooled float[16*256]
//   [XT_OFF,..) : xt bf16 [16][34][34][256]  (padded NHWC, zero halo)
//   [WT_OFF,..) : wt bf16 [8][9][256][256]   ([e][r*3+s][co][ci])
#define XT_OFF 17408
#define XT_BYTES (B_*PH*PW*CIN*2)               // 9,469,952
#define WT_OFF (XT_OFF + XT_BYTES)

// async global->LDS, 16B per lane. LDS dest is wave-uniform base + lane*16.
__device__ __forceinline__ void gld_lds16(const void* g, void* l) {
    __builtin_amdgcn_global_load_lds(
        (const __attribute__((address_space(1))) unsigned int*)g,
        (__attribute__((address_space(3))) unsigned int*)l,
        16, 0, 0);
}

// ---------------- Kernel 1: global average pool ----------------
__global__ void pool_kernel(const float* __restrict__ x, float* __restrict__ pooled) {
    int b = blockIdx.x, c = blockIdx.y;
    const float4* p = (const float4*)(x + ((size_t)b*CIN + c)*HW);
    int t = threadIdx.x;
    float4 v = p[t];                      // 256 threads * 4 = 1024 elems
    float s = v.x + v.y + v.z + v.w;
    #pragma unroll
    for (int o = 32; o > 0; o >>= 1) s += __shfl_down(s, o, 64);
    __shared__ float wsum[4];
    if ((t & 63) == 0) wsum[t >> 6] = s;
    __syncthreads();
    if (t == 0) pooled[b*CIN + c] = (wsum[0]+wsum[1]+wsum[2]+wsum[3]) * (1.0f/1024.0f);
}

// ---------------- Kernel 2: logits + argmax -> decisions ----------------
__global__ void decide_kernel(const float* __restrict__ pooled, const float* __restrict__ wc,
                              const float* __restrict__ bc, int* __restrict__ dec) {
    int t = threadIdx.x;          // 128 threads: b = t/8, e = t%8
    int b = t >> 3, e = t & 7;
    float acc = bc[e];
    const float4* pp = (const float4*)(pooled + b*CIN);
    const float4* ww = (const float4*)(wc + e*CIN);
    #pragma unroll 4
    for (int i = 0; i < CIN/4; ++i) {
        float4 p = pp[i], w = ww[i];
        acc += p.x*w.x + p.y*w.y + p.z*w.z + p.w*w.w;
    }
    __shared__ float lg[16][8];
    lg[b][e] = acc;
    __syncthreads();
    if (e == 0) {
        float best = lg[b][0]; int bi = 0;
        #pragma unroll
        for (int j = 1; j < 8; ++j) { if (lg[b][j] > best) { best = lg[b][j]; bi = j; } }
        dec[b] = bi;
    }
}

// ---------------- Kernel 3: x NCHW fp32 -> padded NHWC bf16 ----------------
__global__ void xpose_kernel(const float* __restrict__ x, unsigned short* __restrict__ xt) {
    // grid (16, 32, 8): b, hw-tile (32 hw), ci-tile (32 ci); 256 threads
    int b = blockIdx.x;
    int hw0 = blockIdx.y * 32;
    int ci0 = blockIdx.z * 32;
    __shared__ float tile[32][33];
    int t = threadIdx.x;
    int j = t & 31;      // hw within tile (read phase)
    int i = t >> 5;      // ci sub-row 0..7
    #pragma unroll
    for (int p = 0; p < 4; ++p)
        tile[i + p*8][j] = x[((size_t)b*CIN + ci0 + i + p*8)*HW + hw0 + j];
    __syncthreads();
    int cw = t & 31;     // ci within tile (write phase)
    int rw = t >> 5;     // hw sub-row 0..7
    #pragma unroll
    for (int p = 0; p < 4; ++p) {
        int hw = hw0 + rw + p*8;
        int h = hw >> 5, w = hw & 31;
        __hip_bfloat16 hv = __float2bfloat16(tile[cw][rw + p*8]);
        xt[(((size_t)b*PH + h + 1)*PW + (w + 1))*CIN + ci0 + cw] = *(unsigned short*)&hv;
    }
}

// ---------------- Kernel 4: we [e][co][ci][3][3] fp32 -> wt [e][rs][co][ci] bf16 ----------------
__global__ void wpose_kernel(const float* __restrict__ we, unsigned short* __restrict__ wt) {
    // block = (e, co): 2048 blocks, 256 threads; coalesced read through LDS
    int e = blockIdx.x >> 8, co = blockIdx.x & 255;
    __shared__ float buf[CIN*9];
    const float* src = we + ((size_t)e*COUT + co)*CIN*9;
    int t = threadIdx.x;
    #pragma unroll
    for (int k = 0; k < 9; ++k) buf[t + k*256] = src[t + k*256];
    __syncthreads();
    // thread t = ci; stride-9 LDS read is conflict-free (odd stride)
    #pragma unroll
    for (int rs = 0; rs < 9; ++rs) {
        __hip_bfloat16 h = __float2bfloat16(buf[t*9 + rs]);
        wt[(((size_t)e*9 + rs)*COUT + co)*CIN + t] = *(unsigned short*)&h;
    }
}

// ---------------- Kernel 5: shift-decomposed implicit-GEMM conv + gather-write ----------------
// Double-buffered, software-pipelined, XOR-bank-swizzled.
// grid: x = mt*8+nt (16 tiles of the 256x1024 output), y = b (16), z = e (8); 256 threads
__global__ __launch_bounds__(256) void conv_kernel(
    const unsigned short* __restrict__ xt, const unsigned short* __restrict__ wt,
    const float* __restrict__ be, const int* __restrict__ dec,
    float* __restrict__ out) {

    int tile = blockIdx.x;
    int b = blockIdx.y;
    int e = blockIdx.z;
    int mt = tile >> 3, nt = tile & 7;

    int dcs[16];
    #pragma unroll
    for (int i = 0; i < 16; ++i) dcs[i] = dec[i];
    bool active = false;
    #pragma unroll
    for (int i = 0; i < 16; ++i) active |= (dcs[i] == e);
    if (!active) return;   // uniform across block

    // Chunk-addressed LDS (16 B chunks), XOR-swizzled: global chunk (row, g)
    // lives at LDS chunk row*4 + (g ^ ((row>>1)&3)).  XOR is involutive, so
    // readers apply the same transform.  This makes the 16-lane stride-4-chunk
    // frag reads at worst 2-way bank aliased (free) instead of 8-way.
    // sA[2]: 512 chunks each (A tile 128 rows x 4 ci-chunks), 8 KB each.
    // sB[2]: 1024 chunks each (816 live: 6x34 halo rows x 4 ci-chunks), 16 KB each.
    __shared__ __align__(16) unsigned short sA[2][512*8];
    __shared__ __align__(16) unsigned short sB[2][1024*8];

    int t = threadIdx.x;
    int wave = t >> 6, lane = t & 63;
    int wm = wave >> 1, wn = wave & 1;     // 2x2 wave grid, 64x64 per wave
    int kg = lane >> 4, ln = lane & 15;

    int ph0 = nt * 4;       // padded halo start row
    int co0 = mt * 128;

    floatx4 acc[4][4];
    #pragma unroll
    for (int i = 0; i < 4; ++i)
        #pragma unroll
        for (int j = 0; j < 4; ++j) acc[i][j] = (floatx4)0.0f;

    const unsigned short* xb = xt + ((size_t)b*PH + ph0)*PW*CIN;   // halo region base (contiguous 6x34 rows)
    const unsigned short* wb = wt + (size_t)e*9*COUT*CIN + (size_t)co0*CIN;

    // ---- staging helpers (16 B/lane, lane-linear LDS dest, swizzled source) ----
    auto stageA = [&](int ck, int sh, int buf) {
        const unsigned short* wsrc = wb + (size_t)sh*COUT*CIN + ck*32;
        #pragma unroll
        for (int k = 0; k < 2; ++k) {
            int c = t + k*256;
            int row = c >> 2, gs = c & 3;
            int g = gs ^ ((row >> 1) & 3);
            gld_lds16(wsrc + (size_t)row*CIN + g*8, &sA[buf][c*8]);
        }
    };
    auto stageB = [&](int ck, int buf) {
        const unsigned short* xsrc = xb + ck*32;
        #pragma unroll
        for (int k = 0; k < 3; ++k) {
            int c = t + k*256;
            int rB = c >> 2, gs = c & 3;
            int g = gs ^ ((rB >> 1) & 3);
            gld_lds16(xsrc + (size_t)rB*CIN + g*8, &sB[buf][c*8]);
        }
        if (t < 64) {                     // wave-uniform: chunks 768..831 (816..831 dead-clamped)
            int c = t + 768;
            int cc = c < 816 ? c : 815;
            int rB = cc >> 2, gs = cc & 3;
            int g = gs ^ ((rB >> 1) & 3);
            gld_lds16(xsrc + (size_t)rB*CIN + g*8, &sB[buf][c*8]);
        }
    };

    // ---- prologue: stage iteration 0 ----
    stageB(0, 0);
    stageA(0, 0, 0);
    __syncthreads();

    // ---- main loop: it = ck*9+sh; sA parity = it&1, sB parity = ck&1 ----
    for (int ck = 0; ck < 8; ++ck) {
        for (int sh = 0; sh < 9; ++sh) {
            int it = ck*9 + sh;
            int ab = it & 1, bb_ = ck & 1;

            // prefetch next iteration's tiles into the alternate buffers
            if (sh < 8) {
                stageA(ck, sh + 1, ab ^ 1);
            } else if (ck < 7) {
                stageA(ck + 1, 0, ab ^ 1);
                stageB(ck + 1, bb_ ^ 1);
            }

            // frag reads (swizzled)
            short8 a[4], bv[4];
            #pragma unroll
            for (int im = 0; im < 4; ++im) {
                int row = wm*64 + im*16 + ln;
                int cL = row*4 + (kg ^ ((row >> 1) & 3));
                a[im] = *(const short8*)(&sA[ab][cL*8]);
            }
            int r = sh / 3, s = sh - r*3;
            #pragma unroll
            for (int in = 0; in < 4; ++in) {
                int n  = wn*64 + in*16 + ln;
                int hl = n >> 5, wl = n & 31;
                int rB = (hl + r)*34 + (wl + s);
                int cL = rB*4 + (kg ^ ((rB >> 1) & 3));
                bv[in] = *(const short8*)(&sB[bb_][cL*8]);
            }

            #pragma unroll
            for (int im = 0; im < 4; ++im)
                #pragma unroll
                for (int in = 0; in < 4; ++in)
                    acc[im][in] = __builtin_amdgcn_mfma_f32_16x16x32_bf16(a[im], bv[in], acc[im][in], 0, 0, 0);

            // single barrier: (a) all waves' frag reads of current buffers done
            // (lgkmcnt drained), (b) prefetch DMA complete (vmcnt drained) --
            // issued ~(frag-read + 16 MFMA) cycles ago, so mostly hidden.
            __syncthreads();
        }
    }

    // ---- epilogue: bias + relu in place ----
    #pragma unroll
    for (int im = 0; im < 4; ++im) {
        int co = co0 + wm*64 + im*16 + kg*4;
        #pragma unroll
        for (int rg = 0; rg < 4; ++rg) {
            float bvv = be[e*COUT + co + rg];
            #pragma unroll
            for (int in = 0; in < 4; ++in) {
                float v = acc[im][in][rg] + bvv;
                acc[im][in][rg] = v > 0.0f ? v : 0.0f;
            }
        }
    }
    // ---- write to every output slot i with dec[i]==e ----
    for (int i = 0; i < 16; ++i) {
        if (dcs[i] != e) continue;
        float* ob = out + (size_t)(i*16 + b)*COUT*HW;
        #pragma unroll
        for (int im = 0; im < 4; ++im) {
            int co = co0 + wm*64 + im*16 + kg*4;
            #pragma unroll
            for (int in = 0; in < 4; ++in) {
                int hw = nt*128 + wn*64 + in*16 + ln;
                #pragma unroll
                for (int rg = 0; rg < 4; ++rg)
                    ob[(size_t)(co + rg)*HW + hw] = acc[im][in][rg];
            }
        }
    }
}

extern "C" void kernel_launch(void* const* d_in, const int* in_sizes, int n_in,
                              void* d_out, int out_size, void* d_ws, size_t ws_size,
                              hipStream_t stream) {
    const float* x  = (const float*)d_in[0];
    const float* wc = (const float*)d_in[1];
    const float* bc = (const float*)d_in[2];
    const float* we = (const float*)d_in[3];
    const float* be = (const float*)d_in[4];
    float* out = (float*)d_out;

    char* ws = (char*)d_ws;
    int*   dec    = (int*)ws;
    float* pooled = (float*)(ws + 64);
    unsigned short* xt = (unsigned short*)(ws + XT_OFF);
    unsigned short* wt = (unsigned short*)(ws + WT_OFF);

    // zero the padded halo of xt (ws is re-poisoned 0xAA before every launch)
    hipMemsetAsync(xt, 0, XT_BYTES, stream);

    pool_kernel  <<<dim3(16, 256), 256, 0, stream>>>(x, pooled);
    decide_kernel<<<1, 128, 0, stream>>>(pooled, wc, bc, dec);
    xpose_kernel <<<dim3(16, 32, 8), 256, 0, stream>>>(x, xt);
    wpose_kernel <<<2048, 256, 0, stream>>>(we, wt);
    conv_kernel  <<<dim3(16, 16, 8), 256, 0, stream>>>(xt, wt, be, dec, out);
}